// Round 1
// baseline (300.152 us; speedup 1.0000x reference)
//
#include <hip/hip_runtime.h>
#include <hip/hip_bf16.h>
#include <cstdint>

#define HDIM 128
#define NEG_SLOPE 0.01f

// ---------------------------------------------------------------------------
// K1: messages[N,128] = node_emb[N,128] @ W1^T   (C[n,h] = sum_k A[n,k]*W1[h,k])
// Block: 256 threads, 64 rows x 128 cols per block.
// LDS: W1 (row-major, padded) + A tile (padded). Thread tile: 4 rows x 8 cols.
// ---------------------------------------------------------------------------
#define K1_ROWS 64
#define LPAD 132   // 128 + 4 pad, keeps 16B alignment for float4 LDS ops

__global__ __launch_bounds__(256, 1)
void k1_messages(const float* __restrict__ A, const float* __restrict__ W1,
                 float* __restrict__ msg, int N) {
    __shared__ float W1s[HDIM][LPAD];
    __shared__ float As[K1_ROWS][LPAD];
    const int tid  = threadIdx.x;
    const int row0 = blockIdx.x * K1_ROWS;

    // load W1 (16384 floats) as float4, no transpose
    for (int i = tid; i < HDIM * HDIM / 4; i += 256) {
        int h = (i * 4) >> 7;
        int k = (i * 4) & 127;
        float4 v = reinterpret_cast<const float4*>(W1)[i];
        *reinterpret_cast<float4*>(&W1s[h][k]) = v;
    }
    // load A tile (64x128) as float4
    for (int i = tid; i < K1_ROWS * HDIM / 4; i += 256) {
        int r = (i * 4) >> 7;
        int k = (i * 4) & 127;
        int gr = row0 + r;
        float4 v = make_float4(0.f, 0.f, 0.f, 0.f);
        if (gr < N) v = reinterpret_cast<const float4*>(A)[(size_t)gr * 32 + (k >> 2)];
        *reinterpret_cast<float4*>(&As[r][k]) = v;
    }
    __syncthreads();

    const int row_t = tid & 15;   // 0..15
    const int col_t = tid >> 4;   // 0..15
    const int h0 = col_t * 8;

    float acc[4][8];
#pragma unroll
    for (int r = 0; r < 4; ++r)
#pragma unroll
        for (int c = 0; c < 8; ++c) acc[r][c] = 0.f;

    for (int k0 = 0; k0 < HDIM; k0 += 4) {
        float4 a[4];
#pragma unroll
        for (int r = 0; r < 4; ++r)
            a[r] = *reinterpret_cast<const float4*>(&As[row_t + 16 * r][k0]);
#pragma unroll
        for (int c = 0; c < 8; ++c) {
            float4 w = *reinterpret_cast<const float4*>(&W1s[h0 + c][k0]);
#pragma unroll
            for (int r = 0; r < 4; ++r) {
                acc[r][c] += a[r].x * w.x + a[r].y * w.y + a[r].z * w.z + a[r].w * w.w;
            }
        }
    }

#pragma unroll
    for (int r = 0; r < 4; ++r) {
        int gr = row0 + row_t + 16 * r;
        if (gr < N) {
            float4 o0 = make_float4(acc[r][0], acc[r][1], acc[r][2], acc[r][3]);
            float4 o1 = make_float4(acc[r][4], acc[r][5], acc[r][6], acc[r][7]);
            float4* dst = reinterpret_cast<float4*>(&msg[(size_t)gr * HDIM + h0]);
            dst[0] = o0;
            dst[1] = o1;
        }
    }
}

// ---------------------------------------------------------------------------
// K1b: a_src[n] = msg[n,:]·W2[0:128], a_dst[n] = msg[n,:]·W2[128:256]
// one wave per node, float2 per lane
// ---------------------------------------------------------------------------
__global__ __launch_bounds__(256)
void k1b_nodedots(const float* __restrict__ msg, const float* __restrict__ W2,
                  float* __restrict__ a_src, float* __restrict__ a_dst, int N) {
    const int tid  = threadIdx.x;
    const int wid  = tid >> 6;
    const int lane = tid & 63;
    const int n = blockIdx.x * 4 + wid;
    if (n >= N) return;
    float2 mv = *reinterpret_cast<const float2*>(&msg[(size_t)n * HDIM + lane * 2]);
    float2 wa = *reinterpret_cast<const float2*>(&W2[lane * 2]);
    float2 wb = *reinterpret_cast<const float2*>(&W2[HDIM + lane * 2]);
    float pa = mv.x * wa.x + mv.y * wa.y;
    float pb = mv.x * wb.x + mv.y * wb.y;
#pragma unroll
    for (int m = 1; m <= 32; m <<= 1) {
        pa += __shfl_xor(pa, m);
        pb += __shfl_xor(pb, m);
    }
    if (lane == 0) {
        a_src[n] = pa;
        a_dst[n] = pb;
    }
}

// ---------------------------------------------------------------------------
// K2: per-edge logits. 32 lanes per edge (float4 each), shuffle-reduce.
// logit = leaky( edge_emb[e]·W2[256:384] + a_src[start[e]] + a_dst[end[e]] )
// ---------------------------------------------------------------------------
__global__ __launch_bounds__(256)
void k2_edgelogits(const float* __restrict__ edge_emb, const float* __restrict__ W2,
                   const int* __restrict__ start, const int* __restrict__ end,
                   const float* __restrict__ a_src, const float* __restrict__ a_dst,
                   float* __restrict__ logits, int E) {
    const int tid = threadIdx.x;
    const int sub = tid & 31;
    const int e = blockIdx.x * 8 + (tid >> 5);
    if (e >= E) return;
    float4 ev = reinterpret_cast<const float4*>(edge_emb)[(size_t)e * 32 + sub];
    float4 wc = reinterpret_cast<const float4*>(W2 + 2 * HDIM)[sub];
    float p = ev.x * wc.x + ev.y * wc.y + ev.z * wc.z + ev.w * wc.w;
#pragma unroll
    for (int m = 1; m <= 16; m <<= 1) p += __shfl_xor(p, m);
    if (sub == 0) {
        float l = p + a_src[start[e]] + a_dst[end[e]];
        logits[e] = (l >= 0.f) ? l : NEG_SLOPE * l;
    }
}

// ---------------------------------------------------------------------------
// K3: per-node segment softmax + weighted scatter-sum of msg[end[e]].
// start_nodes is sorted -> binary search segment bounds. Block=128 (one col
// per thread).
// ---------------------------------------------------------------------------
__device__ __forceinline__ int lower_bound_i(const int* __restrict__ arr, int n, int key) {
    int lo = 0, hi = n;
    while (lo < hi) {
        int mid = (lo + hi) >> 1;
        if (arr[mid] < key) lo = mid + 1; else hi = mid;
    }
    return lo;
}

__global__ __launch_bounds__(128)
void k3_aggregate(const float* __restrict__ logits, const int* __restrict__ start,
                  const int* __restrict__ end, const float* __restrict__ msg,
                  float* __restrict__ out, int N, int E) {
    const int n = blockIdx.x;
    const int tid = threadIdx.x;
    const int wid = tid >> 6;
    const int lane = tid & 63;

    const int lo = lower_bound_i(start, E, n);
    const int hi = lower_bound_i(start, E, n + 1);

    if (lo >= hi) {
        out[(size_t)n * HDIM + tid] = 0.f;
        return;
    }

    __shared__ float redm[2];
    __shared__ float reds[2];

    // segment max
    float m = -3.0e38f;
    for (int i = lo + tid; i < hi; i += 128) m = fmaxf(m, logits[i]);
#pragma unroll
    for (int k = 1; k <= 32; k <<= 1) m = fmaxf(m, __shfl_xor(m, k));
    if (lane == 0) redm[wid] = m;
    __syncthreads();
    m = fmaxf(redm[0], redm[1]);

    // segment sum of exp
    float s = 0.f;
    for (int i = lo + tid; i < hi; i += 128) s += __expf(logits[i] - m);
#pragma unroll
    for (int k = 1; k <= 32; k <<= 1) s += __shfl_xor(s, k);
    if (lane == 0) reds[wid] = s;
    __syncthreads();
    s = reds[0] + reds[1];
    const float inv = 1.f / s;

    // weighted accumulate: out[n,tid] = sum_e attn_e * msg[end[e], tid]
    float acc = 0.f;
    for (int e = lo; e < hi; ++e) {
        float w = __expf(logits[e] - m) * inv;
        int d = end[e];
        acc += w * msg[(size_t)d * HDIM + tid];
    }
    out[(size_t)n * HDIM + tid] = acc;
}

// ---------------------------------------------------------------------------
extern "C" void kernel_launch(void* const* d_in, const int* in_sizes, int n_in,
                              void* d_out, int out_size, void* d_ws, size_t ws_size,
                              hipStream_t stream) {
    const float* node_emb = (const float*)d_in[0];
    const float* edge_emb = (const float*)d_in[1];
    const int*   start    = (const int*)d_in[2];
    const int*   end      = (const int*)d_in[3];
    const float* W1       = (const float*)d_in[4];
    const float* W2       = (const float*)d_in[5];
    float* out = (float*)d_out;

    const int N = in_sizes[0] / HDIM;
    const int E = in_sizes[2];

    // workspace layout
    uint8_t* ws = (uint8_t*)d_ws;
    size_t off = 0;
    auto alloc = [&](size_t bytes) {
        void* p = ws + off;
        off = (off + bytes + 511) & ~(size_t)511;
        return p;
    };
    float* msg    = (float*)alloc((size_t)N * HDIM * sizeof(float));
    float* a_src  = (float*)alloc((size_t)N * sizeof(float));
    float* a_dst  = (float*)alloc((size_t)N * sizeof(float));
    float* logits = (float*)alloc((size_t)E * sizeof(float));

    // K1: messages
    {
        int blocks = (N + K1_ROWS - 1) / K1_ROWS;
        k1_messages<<<blocks, 256, 0, stream>>>(node_emb, W1, msg, N);
    }
    // K1b: per-node dots with W2 halves
    {
        int blocks = (N + 3) / 4;
        k1b_nodedots<<<blocks, 256, 0, stream>>>(msg, W2, a_src, a_dst, N);
    }
    // K2: edge logits
    {
        int blocks = (E + 7) / 8;
        k2_edgelogits<<<blocks, 256, 0, stream>>>(edge_emb, W2, start, end,
                                                  a_src, a_dst, logits, E);
    }
    // K3: segment softmax + aggregate
    {
        k3_aggregate<<<N, 128, 0, stream>>>(logits, start, end, msg, out, N, E);
    }
}

// Round 3
// 245.284 us; speedup vs baseline: 1.2237x; 1.2237x over previous
//
#include <hip/hip_runtime.h>
#include <hip/hip_bf16.h>
#include <cstdint>

#define HDIM 128
#define NEG_SLOPE 0.01f

// ---------------------------------------------------------------------------
// K0: row_ptr build. start_nodes is sorted; row_ptr[n] = lower_bound(start, n).
// One pass over edges; each edge fills the (usually tiny) gap it closes.
// ---------------------------------------------------------------------------
__global__ __launch_bounds__(256)
void k0_rowptr(const int* __restrict__ start, int* __restrict__ row_ptr,
               int N, int E) {
    int e = blockIdx.x * 256 + threadIdx.x;
    if (e >= E) return;
    int s = start[e];
    if (e == 0) {
        for (int n = 0; n <= s; ++n) row_ptr[n] = 0;
    }
    int snext = (e + 1 < E) ? start[e + 1] : N;
    for (int n = s + 1; n <= snext; ++n) row_ptr[n] = e + 1;
}

// ---------------------------------------------------------------------------
// K1: messages[N,128] = node_emb @ W1^T, fused with per-node dots:
//     a_src[n] = msg[n]·W2[0:128], a_dst[n] = msg[n]·W2[128:256].
// 256 threads, 64 rows/block. W1 in LDS with BIJECTIVE XOR column swizzle:
//   granule g of row h stored at h*128 + (g ^ ((h>>3)&3))*4.
// Read: 4 rows/wave {c,c+8,c+16,c+24} get XOR keys 0..3 -> disjoint bank sets
// -> conflict-free. A read from global (L1-resident). Thread tile 4x8.
// LDS 72.5 KB -> 2 blocks/CU.
// ---------------------------------------------------------------------------
#define K1_ROWS 64

__global__ __launch_bounds__(256, 2)
void k1_messages(const float* __restrict__ A, const float* __restrict__ W1,
                 const float* __restrict__ W2, float* __restrict__ msg,
                 float* __restrict__ a_src, float* __restrict__ a_dst, int N) {
    __shared__ float smem[HDIM * HDIM + 2 * 64 * 17];
    float* W1s   = smem;                 // [128][128], XOR-swizzled granules
    float* out_s = smem;                 // aliases W1s after k-loop, stride 132
    float* red_a = smem + HDIM * HDIM;   // [64][17]
    float* red_b = red_a + 64 * 17;      // [64][17]

    const int tid  = threadIdx.x;
    const int row0 = blockIdx.x * K1_ROWS;

    // stage W1 into LDS (float4 granules, XOR swizzle; bijective within row)
    for (int i = tid; i < HDIM * HDIM / 4; i += 256) {
        int h = i >> 5;        // row
        int g = i & 31;        // float4 granule within row
        float4 v = reinterpret_cast<const float4*>(W1)[i];
        int gs = g ^ ((h >> 3) & 3);
        *reinterpret_cast<float4*>(&W1s[h * HDIM + gs * 4]) = v;
    }
    __syncthreads();

    const int row_t = tid & 15;   // 0..15
    const int col_t = tid >> 4;   // 0..15
    const int h0 = col_t * 8;
    const int sxor = col_t & 3;          // == ((h0+c)>>3)&3 for c in 0..7
    const int wbase = h0 * HDIM;

    int gr[4];
#pragma unroll
    for (int r = 0; r < 4; ++r) {
        int g = row0 + row_t + 16 * r;
        gr[r] = (g < N) ? g : (N - 1);   // clamp; stores guarded later
    }

    float acc[4][8];
#pragma unroll
    for (int r = 0; r < 4; ++r)
#pragma unroll
        for (int c = 0; c < 8; ++c) acc[r][c] = 0.f;

#pragma unroll 2
    for (int k0 = 0; k0 < HDIM; k0 += 4) {
        const int kk = (((k0 >> 2) ^ sxor) << 2);   // swizzled column offset
        float4 a[4];
#pragma unroll
        for (int r = 0; r < 4; ++r)
            a[r] = *reinterpret_cast<const float4*>(&A[(size_t)gr[r] * HDIM + k0]);
#pragma unroll
        for (int c = 0; c < 8; ++c) {
            float4 w = *reinterpret_cast<const float4*>(&W1s[wbase + c * HDIM + kk]);
#pragma unroll
            for (int r = 0; r < 4; ++r) {
                acc[r][c] += a[r].x * w.x + a[r].y * w.y + a[r].z * w.z + a[r].w * w.w;
            }
        }
    }

    // per-thread partial dots with W2 halves (W2 L1-cached broadcast)
    float pa[4], pb[4];
#pragma unroll
    for (int r = 0; r < 4; ++r) { pa[r] = 0.f; pb[r] = 0.f; }
#pragma unroll
    for (int c = 0; c < 8; ++c) {
        float wa = W2[h0 + c];
        float wb = W2[HDIM + h0 + c];
#pragma unroll
        for (int r = 0; r < 4; ++r) {
            pa[r] += acc[r][c] * wa;
            pb[r] += acc[r][c] * wb;
        }
    }

    __syncthreads();   // everyone done reading W1s

    // stage outputs (stride 132: row_t spreads banks by 4 -> free) + partials
#pragma unroll
    for (int r = 0; r < 4; ++r) {
        int lrow = row_t + 16 * r;
        float4 o0 = make_float4(acc[r][0], acc[r][1], acc[r][2], acc[r][3]);
        float4 o1 = make_float4(acc[r][4], acc[r][5], acc[r][6], acc[r][7]);
        *reinterpret_cast<float4*>(&out_s[lrow * 132 + h0])     = o0;
        *reinterpret_cast<float4*>(&out_s[lrow * 132 + h0 + 4]) = o1;
        red_a[lrow * 17 + col_t] = pa[r];
        red_b[lrow * 17 + col_t] = pb[r];
    }
    __syncthreads();

    // coalesced store of msg
    for (int i = tid; i < K1_ROWS * 32; i += 256) {
        int lrow = i >> 5;
        int c4   = i & 31;
        int g = row0 + lrow;
        if (g < N) {
            float4 v = *reinterpret_cast<const float4*>(&out_s[lrow * 132 + c4 * 4]);
            reinterpret_cast<float4*>(&msg[(size_t)g * HDIM])[c4] = v;
        }
    }
    // a_src / a_dst reduction (64 rows, 16 partials each)
    if (tid < K1_ROWS) {
        int g = row0 + tid;
        if (g < N) {
            float sa = 0.f, sb = 0.f;
#pragma unroll
            for (int j = 0; j < 16; ++j) {
                sa += red_a[tid * 17 + j];
                sb += red_b[tid * 17 + j];
            }
            a_src[g] = sa;
            a_dst[g] = sb;
        }
    }
}

// ---------------------------------------------------------------------------
// K2: per-edge logits. 32 lanes per edge (float4 each), shuffle-reduce.
// logit = leaky( edge_emb[e]·W2[256:384] + a_src[start[e]] + a_dst[end[e]] )
// ---------------------------------------------------------------------------
__global__ __launch_bounds__(256)
void k2_edgelogits(const float* __restrict__ edge_emb, const float* __restrict__ W2,
                   const int* __restrict__ start, const int* __restrict__ end,
                   const float* __restrict__ a_src, const float* __restrict__ a_dst,
                   float* __restrict__ logits, int E) {
    const int tid = threadIdx.x;
    const int sub = tid & 31;
    const int e = blockIdx.x * 8 + (tid >> 5);
    if (e >= E) return;
    float4 ev = reinterpret_cast<const float4*>(edge_emb)[(size_t)e * 32 + sub];
    float4 wc = reinterpret_cast<const float4*>(W2 + 2 * HDIM)[sub];
    float p = ev.x * wc.x + ev.y * wc.y + ev.z * wc.z + ev.w * wc.w;
#pragma unroll
    for (int m = 1; m <= 16; m <<= 1) p += __shfl_xor(p, m);
    if (sub == 0) {
        float l = p + a_src[start[e]] + a_dst[end[e]];
        logits[e] = (l >= 0.f) ? l : NEG_SLOPE * l;
    }
}

// ---------------------------------------------------------------------------
// K3: per-node segment softmax + weighted scatter-sum of msg[end[e]].
// One WAVE per node (float2 per lane). row_ptr gives segment bounds in 2 loads.
// ---------------------------------------------------------------------------
__global__ __launch_bounds__(256)
void k3_aggregate(const float* __restrict__ logits, const int* __restrict__ row_ptr,
                  const int* __restrict__ end, const float* __restrict__ msg,
                  float* __restrict__ out, int N) {
    const int wid  = threadIdx.x >> 6;
    const int lane = threadIdx.x & 63;
    const int n = blockIdx.x * 4 + wid;
    if (n >= N) return;

    const int lo = row_ptr[n];
    const int hi = row_ptr[n + 1];

    float2 acc = make_float2(0.f, 0.f);
    if (lo < hi) {
        // segment max
        float m = -3.0e38f;
        for (int i = lo + lane; i < hi; i += 64) m = fmaxf(m, logits[i]);
#pragma unroll
        for (int k = 1; k <= 32; k <<= 1) m = fmaxf(m, __shfl_xor(m, k));
        // segment sum of exp
        float s = 0.f;
        for (int i = lo + lane; i < hi; i += 64) s += __expf(logits[i] - m);
#pragma unroll
        for (int k = 1; k <= 32; k <<= 1) s += __shfl_xor(s, k);
        const float inv = 1.f / s;
        // weighted accumulate (wave-uniform w,d; coalesced float2 row gather)
        for (int e = lo; e < hi; ++e) {
            float w = __expf(logits[e] - m) * inv;
            int d = end[e];
            float2 mv = *reinterpret_cast<const float2*>(&msg[(size_t)d * HDIM + lane * 2]);
            acc.x += w * mv.x;
            acc.y += w * mv.y;
        }
    }
    *reinterpret_cast<float2*>(&out[(size_t)n * HDIM + lane * 2]) = acc;
}

// ---------------------------------------------------------------------------
extern "C" void kernel_launch(void* const* d_in, const int* in_sizes, int n_in,
                              void* d_out, int out_size, void* d_ws, size_t ws_size,
                              hipStream_t stream) {
    const float* node_emb = (const float*)d_in[0];
    const float* edge_emb = (const float*)d_in[1];
    const int*   start    = (const int*)d_in[2];
    const int*   end      = (const int*)d_in[3];
    const float* W1       = (const float*)d_in[4];
    const float* W2       = (const float*)d_in[5];
    float* out = (float*)d_out;

    const int N = in_sizes[0] / HDIM;
    const int E = in_sizes[2];

    uint8_t* ws = (uint8_t*)d_ws;
    size_t off = 0;
    auto alloc = [&](size_t bytes) {
        void* p = ws + off;
        off = (off + bytes + 511) & ~(size_t)511;
        return p;
    };
    float* msg     = (float*)alloc((size_t)N * HDIM * sizeof(float));
    float* a_src   = (float*)alloc((size_t)N * sizeof(float));
    float* a_dst   = (float*)alloc((size_t)N * sizeof(float));
    float* logits  = (float*)alloc((size_t)E * sizeof(float));
    int*   row_ptr = (int*)alloc((size_t)(N + 1) * sizeof(int));

    // K0: row_ptr (independent of K1)
    k0_rowptr<<<(E + 255) / 256, 256, 0, stream>>>(start, row_ptr, N, E);
    // K1: messages + fused a_src/a_dst
    k1_messages<<<(N + K1_ROWS - 1) / K1_ROWS, 256, 0, stream>>>(
        node_emb, W1, W2, msg, a_src, a_dst, N);
    // K2: edge logits
    k2_edgelogits<<<(E + 7) / 8, 256, 0, stream>>>(edge_emb, W2, start, end,
                                                   a_src, a_dst, logits, E);
    // K3: segment softmax + aggregate (one wave per node)
    k3_aggregate<<<(N + 3) / 4, 256, 0, stream>>>(logits, row_ptr, end, msg, out, N);
}

// Round 4
// 179.903 us; speedup vs baseline: 1.6684x; 1.3634x over previous
//
#include <hip/hip_runtime.h>
#include <hip/hip_bf16.h>
#include <cstdint>

#define HDIM 128
#define NEG_SLOPE 0.01f

// ---------------------------------------------------------------------------
// K0: row_ptr build. start_nodes is sorted; row_ptr[n] = lower_bound(start, n).
// ---------------------------------------------------------------------------
__global__ __launch_bounds__(256)
void k0_rowptr(const int* __restrict__ start, int* __restrict__ row_ptr,
               int N, int E) {
    int e = blockIdx.x * 256 + threadIdx.x;
    if (e >= E) return;
    int s = start[e];
    if (e == 0) {
        for (int n = 0; n <= s; ++n) row_ptr[n] = 0;
    }
    int snext = (e + 1 < E) ? start[e + 1] : N;
    for (int n = s + 1; n <= snext; ++n) row_ptr[n] = e + 1;
}

// ---------------------------------------------------------------------------
// K1: messages[N,128] = node_emb @ W1^T, fused with per-node dots:
//     a_src[n] = msg[n]·W2[0:128], a_dst[n] = msg[n]·W2[128:256].
// W1 in LDS with bijective XOR column-granule swizzle (conflict-free reads).
// ---------------------------------------------------------------------------
#define K1_ROWS 64

__global__ __launch_bounds__(256, 2)
void k1_messages(const float* __restrict__ A, const float* __restrict__ W1,
                 const float* __restrict__ W2, float* __restrict__ msg,
                 float* __restrict__ a_src, float* __restrict__ a_dst, int N) {
    __shared__ float smem[HDIM * HDIM + 2 * 64 * 17];
    float* W1s   = smem;                 // [128][128], XOR-swizzled granules
    float* out_s = smem;                 // aliases W1s after k-loop, stride 132
    float* red_a = smem + HDIM * HDIM;   // [64][17]
    float* red_b = red_a + 64 * 17;      // [64][17]

    const int tid  = threadIdx.x;
    const int row0 = blockIdx.x * K1_ROWS;

    for (int i = tid; i < HDIM * HDIM / 4; i += 256) {
        int h = i >> 5;
        int g = i & 31;
        float4 v = reinterpret_cast<const float4*>(W1)[i];
        int gs = g ^ ((h >> 3) & 3);
        *reinterpret_cast<float4*>(&W1s[h * HDIM + gs * 4]) = v;
    }
    __syncthreads();

    const int row_t = tid & 15;
    const int col_t = tid >> 4;
    const int h0 = col_t * 8;
    const int sxor = col_t & 3;
    const int wbase = h0 * HDIM;

    int gr[4];
#pragma unroll
    for (int r = 0; r < 4; ++r) {
        int g = row0 + row_t + 16 * r;
        gr[r] = (g < N) ? g : (N - 1);
    }

    float acc[4][8];
#pragma unroll
    for (int r = 0; r < 4; ++r)
#pragma unroll
        for (int c = 0; c < 8; ++c) acc[r][c] = 0.f;

#pragma unroll 2
    for (int k0 = 0; k0 < HDIM; k0 += 4) {
        const int kk = (((k0 >> 2) ^ sxor) << 2);
        float4 a[4];
#pragma unroll
        for (int r = 0; r < 4; ++r)
            a[r] = *reinterpret_cast<const float4*>(&A[(size_t)gr[r] * HDIM + k0]);
#pragma unroll
        for (int c = 0; c < 8; ++c) {
            float4 w = *reinterpret_cast<const float4*>(&W1s[wbase + c * HDIM + kk]);
#pragma unroll
            for (int r = 0; r < 4; ++r) {
                acc[r][c] += a[r].x * w.x + a[r].y * w.y + a[r].z * w.z + a[r].w * w.w;
            }
        }
    }

    float pa[4], pb[4];
#pragma unroll
    for (int r = 0; r < 4; ++r) { pa[r] = 0.f; pb[r] = 0.f; }
#pragma unroll
    for (int c = 0; c < 8; ++c) {
        float wa = W2[h0 + c];
        float wb = W2[HDIM + h0 + c];
#pragma unroll
        for (int r = 0; r < 4; ++r) {
            pa[r] += acc[r][c] * wa;
            pb[r] += acc[r][c] * wb;
        }
    }

    __syncthreads();

#pragma unroll
    for (int r = 0; r < 4; ++r) {
        int lrow = row_t + 16 * r;
        float4 o0 = make_float4(acc[r][0], acc[r][1], acc[r][2], acc[r][3]);
        float4 o1 = make_float4(acc[r][4], acc[r][5], acc[r][6], acc[r][7]);
        *reinterpret_cast<float4*>(&out_s[lrow * 132 + h0])     = o0;
        *reinterpret_cast<float4*>(&out_s[lrow * 132 + h0 + 4]) = o1;
        red_a[lrow * 17 + col_t] = pa[r];
        red_b[lrow * 17 + col_t] = pb[r];
    }
    __syncthreads();

    for (int i = tid; i < K1_ROWS * 32; i += 256) {
        int lrow = i >> 5;
        int c4   = i & 31;
        int g = row0 + lrow;
        if (g < N) {
            float4 v = *reinterpret_cast<const float4*>(&out_s[lrow * 132 + c4 * 4]);
            reinterpret_cast<float4*>(&msg[(size_t)g * HDIM])[c4] = v;
        }
    }
    if (tid < K1_ROWS) {
        int g = row0 + tid;
        if (g < N) {
            float sa = 0.f, sb = 0.f;
#pragma unroll
            for (int j = 0; j < 16; ++j) {
                sa += red_a[tid * 17 + j];
                sb += red_b[tid * 17 + j];
            }
            a_src[g] = sa;
            a_dst[g] = sb;
        }
    }
}

// ---------------------------------------------------------------------------
// K23: fused edge-logit + online segment softmax + weighted aggregate.
// One wave per node. Half-wave (32 lanes x float4) per edge, 2 edges in
// flight. Edges of a node are contiguous (start sorted) -> edge_emb read is
// a sequential HBM stream. Online softmax with defer-style rescale (rescale
// only when l > running max). Cross-half merge at the end via shfl_xor(32).
// ---------------------------------------------------------------------------
__global__ __launch_bounds__(256)
void k23_fused(const float* __restrict__ edge_emb, const float* __restrict__ W2,
               const int* __restrict__ row_ptr, const int* __restrict__ end,
               const float* __restrict__ a_src, const float* __restrict__ a_dst,
               const float* __restrict__ msg, float* __restrict__ out, int N) {
    const int wid  = threadIdx.x >> 6;
    const int lane = threadIdx.x & 63;
    const int half = lane >> 5;    // 0 or 1
    const int l32  = lane & 31;
    const int n = blockIdx.x * 4 + wid;
    if (n >= N) return;

    const int lo = row_ptr[n];
    const int hi = row_ptr[n + 1];

    if (lo >= hi) {
        if (half == 0)
            *reinterpret_cast<float4*>(&out[(size_t)n * HDIM + l32 * 4]) =
                make_float4(0.f, 0.f, 0.f, 0.f);
        return;
    }

    const float4 wc = reinterpret_cast<const float4*>(W2 + 2 * HDIM)[l32];
    const float asrc = a_src[n];

    float m = -3.0e38f;
    float s = 0.f;
    float4 acc = make_float4(0.f, 0.f, 0.f, 0.f);

    for (int e = lo + half; e < hi; e += 2) {
        float4 ev = reinterpret_cast<const float4*>(edge_emb)[(size_t)e * 32 + l32];
        float p = ev.x * wc.x + ev.y * wc.y + ev.z * wc.z + ev.w * wc.w;
#pragma unroll
        for (int k = 1; k <= 16; k <<= 1) p += __shfl_xor(p, k);  // within half
        int d = end[e];
        float l = p + asrc + a_dst[d];
        l = (l >= 0.f) ? l : NEG_SLOPE * l;
        float4 mv = reinterpret_cast<const float4*>(msg)[(size_t)d * 32 + l32];
        if (l > m) {
            float sc = __expf(m - l);        // exp(-inf)=0 on first edge
            s = s * sc + 1.f;
            acc.x = acc.x * sc + mv.x;
            acc.y = acc.y * sc + mv.y;
            acc.z = acc.z * sc + mv.z;
            acc.w = acc.w * sc + mv.w;
            m = l;
        } else {
            float w = __expf(l - m);
            s += w;
            acc.x += w * mv.x;
            acc.y += w * mv.y;
            acc.z += w * mv.z;
            acc.w += w * mv.w;
        }
    }

    // merge the two half-wave states (empty half: m=-inf -> weight 0)
    float mo = __shfl_xor(m, 32);
    float so = __shfl_xor(s, 32);
    float4 ao;
    ao.x = __shfl_xor(acc.x, 32);
    ao.y = __shfl_xor(acc.y, 32);
    ao.z = __shfl_xor(acc.z, 32);
    ao.w = __shfl_xor(acc.w, 32);
    float mm = fmaxf(m, mo);
    float e0 = __expf(m - mm);
    float e1 = __expf(mo - mm);
    float inv = 1.f / (s * e0 + so * e1);
    if (half == 0) {
        float4 r;
        r.x = (acc.x * e0 + ao.x * e1) * inv;
        r.y = (acc.y * e0 + ao.y * e1) * inv;
        r.z = (acc.z * e0 + ao.z * e1) * inv;
        r.w = (acc.w * e0 + ao.w * e1) * inv;
        *reinterpret_cast<float4*>(&out[(size_t)n * HDIM + l32 * 4]) = r;
    }
}

// ---------------------------------------------------------------------------
extern "C" void kernel_launch(void* const* d_in, const int* in_sizes, int n_in,
                              void* d_out, int out_size, void* d_ws, size_t ws_size,
                              hipStream_t stream) {
    const float* node_emb = (const float*)d_in[0];
    const float* edge_emb = (const float*)d_in[1];
    const int*   start    = (const int*)d_in[2];
    const int*   end      = (const int*)d_in[3];
    const float* W1       = (const float*)d_in[4];
    const float* W2       = (const float*)d_in[5];
    float* out = (float*)d_out;

    const int N = in_sizes[0] / HDIM;
    const int E = in_sizes[2];

    uint8_t* ws = (uint8_t*)d_ws;
    size_t off = 0;
    auto alloc = [&](size_t bytes) {
        void* p = ws + off;
        off = (off + bytes + 511) & ~(size_t)511;
        return p;
    };
    float* msg     = (float*)alloc((size_t)N * HDIM * sizeof(float));
    float* a_src   = (float*)alloc((size_t)N * sizeof(float));
    float* a_dst   = (float*)alloc((size_t)N * sizeof(float));
    int*   row_ptr = (int*)alloc((size_t)(N + 1) * sizeof(int));

    // K0: row_ptr (independent of K1)
    k0_rowptr<<<(E + 255) / 256, 256, 0, stream>>>(start, row_ptr, N, E);
    // K1: messages + fused a_src/a_dst
    k1_messages<<<(N + K1_ROWS - 1) / K1_ROWS, 256, 0, stream>>>(
        node_emb, W1, W2, msg, a_src, a_dst, N);
    // K23: fused edge logits + online softmax + aggregate (one wave per node)
    k23_fused<<<(N + 3) / 4, 256, 0, stream>>>(edge_emb, W2, row_ptr, end,
                                               a_src, a_dst, msg, out, N);
}

// Round 5
// 163.011 us; speedup vs baseline: 1.8413x; 1.1036x over previous
//
#include <hip/hip_runtime.h>
#include <hip/hip_bf16.h>
#include <cstdint>

#define HDIM 128
#define NEG_SLOPE 0.01f

__device__ __forceinline__ float bf2f(unsigned short u) {
    return __uint_as_float(((uint32_t)u) << 16);
}
__device__ __forceinline__ unsigned short f2bf(float f) {
    __hip_bfloat16 b = __float2bfloat16(f);
    return *reinterpret_cast<unsigned short*>(&b);
}

// ---------------------------------------------------------------------------
// K0: row_ptr build. start_nodes is sorted; row_ptr[n] = lower_bound(start, n).
// ---------------------------------------------------------------------------
__global__ __launch_bounds__(256)
void k0_rowptr(const int* __restrict__ start, int* __restrict__ row_ptr,
               int N, int E) {
    int e = blockIdx.x * 256 + threadIdx.x;
    if (e >= E) return;
    int s = start[e];
    if (e == 0) {
        for (int n = 0; n <= s; ++n) row_ptr[n] = 0;
    }
    int snext = (e + 1 < E) ? start[e + 1] : N;
    for (int n = s + 1; n <= snext; ++n) row_ptr[n] = e + 1;
}

// ---------------------------------------------------------------------------
// K1: messages = node_emb @ W1^T, stored as BF16 (gather table for K23),
// fused per-node dots a_src[n] = msg·W2[0:128], a_dst[n] = msg·W2[128:256]
// (fp32 accumulators -> fp32 a_src/a_dst; only the V-side msg is bf16).
// W1 in LDS with bijective XOR column-granule swizzle (conflict-free reads).
// LDS 72.5 KB -> 2 blocks/CU.
// ---------------------------------------------------------------------------
#define K1_ROWS 64

__global__ __launch_bounds__(256, 2)
void k1_messages(const float* __restrict__ A, const float* __restrict__ W1,
                 const float* __restrict__ W2, unsigned short* __restrict__ msgb,
                 float* __restrict__ a_src, float* __restrict__ a_dst, int N) {
    __shared__ float W1s[HDIM * HDIM];   // XOR-swizzled granules
    __shared__ float red_a[64 * 17];
    __shared__ float red_b[64 * 17];

    const int tid  = threadIdx.x;
    const int row0 = blockIdx.x * K1_ROWS;

    for (int i = tid; i < HDIM * HDIM / 4; i += 256) {
        int h = i >> 5;
        int g = i & 31;
        float4 v = reinterpret_cast<const float4*>(W1)[i];
        int gs = g ^ ((h >> 3) & 3);
        *reinterpret_cast<float4*>(&W1s[h * HDIM + gs * 4]) = v;
    }
    __syncthreads();

    const int row_t = tid & 15;
    const int col_t = tid >> 4;
    const int h0 = col_t * 8;
    const int sxor = col_t & 3;
    const int wbase = h0 * HDIM;

    int gr[4];
#pragma unroll
    for (int r = 0; r < 4; ++r) {
        int g = row0 + row_t + 16 * r;
        gr[r] = (g < N) ? g : (N - 1);
    }

    float acc[4][8];
#pragma unroll
    for (int r = 0; r < 4; ++r)
#pragma unroll
        for (int c = 0; c < 8; ++c) acc[r][c] = 0.f;

#pragma unroll 2
    for (int k0 = 0; k0 < HDIM; k0 += 4) {
        const int kk = (((k0 >> 2) ^ sxor) << 2);
        float4 a[4];
#pragma unroll
        for (int r = 0; r < 4; ++r)
            a[r] = *reinterpret_cast<const float4*>(&A[(size_t)gr[r] * HDIM + k0]);
#pragma unroll
        for (int c = 0; c < 8; ++c) {
            float4 w = *reinterpret_cast<const float4*>(&W1s[wbase + c * HDIM + kk]);
#pragma unroll
            for (int r = 0; r < 4; ++r) {
                acc[r][c] += a[r].x * w.x + a[r].y * w.y + a[r].z * w.z + a[r].w * w.w;
            }
        }
    }

    // per-thread partial dots with W2 halves
    float pa[4], pb[4];
#pragma unroll
    for (int r = 0; r < 4; ++r) { pa[r] = 0.f; pb[r] = 0.f; }
#pragma unroll
    for (int c = 0; c < 8; ++c) {
        float wa = W2[h0 + c];
        float wb = W2[HDIM + h0 + c];
#pragma unroll
        for (int r = 0; r < 4; ++r) {
            pa[r] += acc[r][c] * wa;
            pb[r] += acc[r][c] * wb;
        }
    }

    // direct bf16 store of msg rows (16B per thread, 64B-line covered per row)
#pragma unroll
    for (int r = 0; r < 4; ++r) {
        int g = row0 + row_t + 16 * r;
        if (g < N) {
            uint4 pk;
            pk.x = (uint32_t)f2bf(acc[r][0]) | ((uint32_t)f2bf(acc[r][1]) << 16);
            pk.y = (uint32_t)f2bf(acc[r][2]) | ((uint32_t)f2bf(acc[r][3]) << 16);
            pk.z = (uint32_t)f2bf(acc[r][4]) | ((uint32_t)f2bf(acc[r][5]) << 16);
            pk.w = (uint32_t)f2bf(acc[r][6]) | ((uint32_t)f2bf(acc[r][7]) << 16);
            *reinterpret_cast<uint4*>(&msgb[(size_t)g * HDIM + h0]) = pk;
        }
        red_a[(row_t + 16 * r) * 17 + col_t] = pa[r];
        red_b[(row_t + 16 * r) * 17 + col_t] = pb[r];
    }
    __syncthreads();

    // a_src / a_dst reduction (64 rows, 16 partials each)
    if (tid < K1_ROWS) {
        int g = row0 + tid;
        if (g < N) {
            float sa = 0.f, sb = 0.f;
#pragma unroll
            for (int j = 0; j < 16; ++j) {
                sa += red_a[tid * 17 + j];
                sb += red_b[tid * 17 + j];
            }
            a_src[g] = sa;
            a_dst[g] = sb;
        }
    }
}

// ---------------------------------------------------------------------------
// K23: fused edge-logit + online segment softmax + weighted aggregate.
// One wave per node; half-wave (32 lanes x float4) per edge, 2 edges/wave in
// flight. edge_emb read is a sequential HBM stream (start sorted). msg gather
// is bf16 (256B/row). Branchless online-softmax update (no half divergence).
// ---------------------------------------------------------------------------
__global__ __launch_bounds__(256)
void k23_fused(const float* __restrict__ edge_emb, const float* __restrict__ W2,
               const int* __restrict__ row_ptr, const int* __restrict__ end,
               const float* __restrict__ a_src, const float* __restrict__ a_dst,
               const unsigned short* __restrict__ msgb, float* __restrict__ out,
               int N) {
    const int wid  = threadIdx.x >> 6;
    const int lane = threadIdx.x & 63;
    const int half = lane >> 5;    // 0 or 1
    const int l32  = lane & 31;
    const int n = blockIdx.x * 4 + wid;
    if (n >= N) return;

    const int lo = row_ptr[n];
    const int hi = row_ptr[n + 1];

    if (lo >= hi) {
        if (half == 0)
            *reinterpret_cast<float4*>(&out[(size_t)n * HDIM + l32 * 4]) =
                make_float4(0.f, 0.f, 0.f, 0.f);
        return;
    }

    const float4 wc = reinterpret_cast<const float4*>(W2 + 2 * HDIM)[l32];
    const float asrc = a_src[n];

    float m = -3.0e38f;
    float s = 0.f;
    float4 acc = make_float4(0.f, 0.f, 0.f, 0.f);

    for (int e = lo + half; e < hi; e += 2) {
        float4 ev = reinterpret_cast<const float4*>(edge_emb)[(size_t)e * 32 + l32];
        int d = end[e];
        float p = ev.x * wc.x + ev.y * wc.y + ev.z * wc.z + ev.w * wc.w;
#pragma unroll
        for (int k = 1; k <= 16; k <<= 1) p += __shfl_xor(p, k);  // within half
        float l = p + asrc + a_dst[d];
        l = (l >= 0.f) ? l : NEG_SLOPE * l;
        ushort4 mu = reinterpret_cast<const ushort4*>(msgb)[(size_t)d * 32 + l32];
        float mn = fmaxf(m, l);
        float sc = __expf(m - mn);   // 0 on first edge
        float w  = __expf(l - mn);
        s = s * sc + w;
        acc.x = acc.x * sc + w * bf2f(mu.x);
        acc.y = acc.y * sc + w * bf2f(mu.y);
        acc.z = acc.z * sc + w * bf2f(mu.z);
        acc.w = acc.w * sc + w * bf2f(mu.w);
        m = mn;
    }

    // merge the two half-wave states (empty half: m=-inf -> weight 0)
    float mo = __shfl_xor(m, 32);
    float so = __shfl_xor(s, 32);
    float4 ao;
    ao.x = __shfl_xor(acc.x, 32);
    ao.y = __shfl_xor(acc.y, 32);
    ao.z = __shfl_xor(acc.z, 32);
    ao.w = __shfl_xor(acc.w, 32);
    float mm = fmaxf(m, mo);
    float e0 = __expf(m - mm);
    float e1 = __expf(mo - mm);
    float inv = 1.f / (s * e0 + so * e1);
    if (half == 0) {
        float4 r;
        r.x = (acc.x * e0 + ao.x * e1) * inv;
        r.y = (acc.y * e0 + ao.y * e1) * inv;
        r.z = (acc.z * e0 + ao.z * e1) * inv;
        r.w = (acc.w * e0 + ao.w * e1) * inv;
        *reinterpret_cast<float4*>(&out[(size_t)n * HDIM + l32 * 4]) = r;
    }
}

// ---------------------------------------------------------------------------
extern "C" void kernel_launch(void* const* d_in, const int* in_sizes, int n_in,
                              void* d_out, int out_size, void* d_ws, size_t ws_size,
                              hipStream_t stream) {
    const float* node_emb = (const float*)d_in[0];
    const float* edge_emb = (const float*)d_in[1];
    const int*   start    = (const int*)d_in[2];
    const int*   end      = (const int*)d_in[3];
    const float* W1       = (const float*)d_in[4];
    const float* W2       = (const float*)d_in[5];
    float* out = (float*)d_out;

    const int N = in_sizes[0] / HDIM;
    const int E = in_sizes[2];

    uint8_t* ws = (uint8_t*)d_ws;
    size_t off = 0;
    auto alloc = [&](size_t bytes) {
        void* p = ws + off;
        off = (off + bytes + 511) & ~(size_t)511;
        return p;
    };
    unsigned short* msgb = (unsigned short*)alloc((size_t)N * HDIM * sizeof(unsigned short));
    float* a_src   = (float*)alloc((size_t)N * sizeof(float));
    float* a_dst   = (float*)alloc((size_t)N * sizeof(float));
    int*   row_ptr = (int*)alloc((size_t)(N + 1) * sizeof(int));

    // K0: row_ptr (independent of K1)
    k0_rowptr<<<(E + 255) / 256, 256, 0, stream>>>(start, row_ptr, N, E);
    // K1: messages (bf16) + fused fp32 a_src/a_dst
    k1_messages<<<(N + K1_ROWS - 1) / K1_ROWS, 256, 0, stream>>>(
        node_emb, W1, W2, msgb, a_src, a_dst, N);
    // K23: fused edge logits + online softmax + aggregate (one wave per node)
    k23_fused<<<(N + 3) / 4, 256, 0, stream>>>(edge_emb, W2, row_ptr, end,
                                               a_src, a_dst, msgb, out, N);
}

// Round 6
// 157.500 us; speedup vs baseline: 1.9057x; 1.0350x over previous
//
#include <hip/hip_runtime.h>
#include <hip/hip_bf16.h>
#include <cstdint>

#define HDIM 128
#define NEG_SLOPE 0.01f

__device__ __forceinline__ float bf2f(unsigned short u) {
    return __uint_as_float(((uint32_t)u) << 16);
}
__device__ __forceinline__ unsigned short f2bf(float f) {
    __hip_bfloat16 b = __float2bfloat16(f);
    return *reinterpret_cast<unsigned short*>(&b);
}

// ---------------------------------------------------------------------------
// K0: row_ptr build. start_nodes is sorted; row_ptr[n] = lower_bound(start, n).
// ---------------------------------------------------------------------------
__global__ __launch_bounds__(256)
void k0_rowptr(const int* __restrict__ start, int* __restrict__ row_ptr,
               int N, int E) {
    int e = blockIdx.x * 256 + threadIdx.x;
    if (e >= E) return;
    int s = start[e];
    if (e == 0) {
        for (int n = 0; n <= s; ++n) row_ptr[n] = 0;
    }
    int snext = (e + 1 < E) ? start[e + 1] : N;
    for (int n = s + 1; n <= snext; ++n) row_ptr[n] = e + 1;
}

// ---------------------------------------------------------------------------
// K1: messages = node_emb @ W1^T, stored as BF16 (gather table for K23),
// fused per-node dots a_src[n] = msg·W2[0:128], a_dst[n] = msg·W2[128:256]
// (fp32 accumulators -> fp32 a_src/a_dst; only the V-side msg is bf16).
// W1 in LDS with bijective XOR column-granule swizzle (conflict-free reads).
// ---------------------------------------------------------------------------
#define K1_ROWS 64

__global__ __launch_bounds__(256, 2)
void k1_messages(const float* __restrict__ A, const float* __restrict__ W1,
                 const float* __restrict__ W2, unsigned short* __restrict__ msgb,
                 float* __restrict__ a_src, float* __restrict__ a_dst, int N) {
    __shared__ float W1s[HDIM * HDIM];   // XOR-swizzled granules
    __shared__ float red_a[64 * 17];
    __shared__ float red_b[64 * 17];

    const int tid  = threadIdx.x;
    const int row0 = blockIdx.x * K1_ROWS;

    for (int i = tid; i < HDIM * HDIM / 4; i += 256) {
        int h = i >> 5;
        int g = i & 31;
        float4 v = reinterpret_cast<const float4*>(W1)[i];
        int gs = g ^ ((h >> 3) & 3);
        *reinterpret_cast<float4*>(&W1s[h * HDIM + gs * 4]) = v;
    }
    __syncthreads();

    const int row_t = tid & 15;
    const int col_t = tid >> 4;
    const int h0 = col_t * 8;
    const int sxor = col_t & 3;
    const int wbase = h0 * HDIM;

    int gr[4];
#pragma unroll
    for (int r = 0; r < 4; ++r) {
        int g = row0 + row_t + 16 * r;
        gr[r] = (g < N) ? g : (N - 1);
    }

    float acc[4][8];
#pragma unroll
    for (int r = 0; r < 4; ++r)
#pragma unroll
        for (int c = 0; c < 8; ++c) acc[r][c] = 0.f;

#pragma unroll 2
    for (int k0 = 0; k0 < HDIM; k0 += 4) {
        const int kk = (((k0 >> 2) ^ sxor) << 2);
        float4 a[4];
#pragma unroll
        for (int r = 0; r < 4; ++r)
            a[r] = *reinterpret_cast<const float4*>(&A[(size_t)gr[r] * HDIM + k0]);
#pragma unroll
        for (int c = 0; c < 8; ++c) {
            float4 w = *reinterpret_cast<const float4*>(&W1s[wbase + c * HDIM + kk]);
#pragma unroll
            for (int r = 0; r < 4; ++r) {
                acc[r][c] += a[r].x * w.x + a[r].y * w.y + a[r].z * w.z + a[r].w * w.w;
            }
        }
    }

    float pa[4], pb[4];
#pragma unroll
    for (int r = 0; r < 4; ++r) { pa[r] = 0.f; pb[r] = 0.f; }
#pragma unroll
    for (int c = 0; c < 8; ++c) {
        float wa = W2[h0 + c];
        float wb = W2[HDIM + h0 + c];
#pragma unroll
        for (int r = 0; r < 4; ++r) {
            pa[r] += acc[r][c] * wa;
            pb[r] += acc[r][c] * wb;
        }
    }

    // direct bf16 store of msg rows
#pragma unroll
    for (int r = 0; r < 4; ++r) {
        int g = row0 + row_t + 16 * r;
        if (g < N) {
            uint4 pk;
            pk.x = (uint32_t)f2bf(acc[r][0]) | ((uint32_t)f2bf(acc[r][1]) << 16);
            pk.y = (uint32_t)f2bf(acc[r][2]) | ((uint32_t)f2bf(acc[r][3]) << 16);
            pk.z = (uint32_t)f2bf(acc[r][4]) | ((uint32_t)f2bf(acc[r][5]) << 16);
            pk.w = (uint32_t)f2bf(acc[r][6]) | ((uint32_t)f2bf(acc[r][7]) << 16);
            *reinterpret_cast<uint4*>(&msgb[(size_t)g * HDIM + h0]) = pk;
        }
        red_a[(row_t + 16 * r) * 17 + col_t] = pa[r];
        red_b[(row_t + 16 * r) * 17 + col_t] = pb[r];
    }
    __syncthreads();

    if (tid < K1_ROWS) {
        int g = row0 + tid;
        if (g < N) {
            float sa = 0.f, sb = 0.f;
#pragma unroll
            for (int j = 0; j < 16; ++j) {
                sa += red_a[tid * 17 + j];
                sb += red_b[tid * 17 + j];
            }
            a_src[g] = sa;
            a_dst[g] = sb;
        }
    }
}

// ---------------------------------------------------------------------------
// K23: fused edge-logit + segment softmax + weighted aggregate.
// One wave per node; half-wave (32 lanes x float4) per edge. BATCHED two-pass:
// pass A loads 8 edges/half (ev, end, a_dst, msg rows) and computes logits
// with independent dep-chains (8 edge-loads in flight -> MLP); pass B takes
// the batch max in registers, ONE rescale per batch, 8 independent exp+FMA.
// Masked slots: clamped indices (in-bounds loads) + -3e38 sentinel; empty
// halves are zeroed by the final cross-half merge (exp(-3e38-mm)=0).
// ---------------------------------------------------------------------------
#define BATCH 8   // edges per half per batch (16 edges per wave batch)

__global__ __launch_bounds__(256)
void k23_fused(const float* __restrict__ edge_emb, const float* __restrict__ W2,
               const int* __restrict__ row_ptr, const int* __restrict__ end,
               const float* __restrict__ a_src, const float* __restrict__ a_dst,
               const unsigned short* __restrict__ msgb, float* __restrict__ out,
               int N) {
    const int wid  = threadIdx.x >> 6;
    const int lane = threadIdx.x & 63;
    const int half = lane >> 5;    // 0 or 1
    const int l32  = lane & 31;
    const int n = blockIdx.x * 4 + wid;
    if (n >= N) return;

    const int lo = row_ptr[n];
    const int hi = row_ptr[n + 1];

    if (lo >= hi) {
        if (half == 0)
            *reinterpret_cast<float4*>(&out[(size_t)n * HDIM + l32 * 4]) =
                make_float4(0.f, 0.f, 0.f, 0.f);
        return;
    }

    const float4 wc = reinterpret_cast<const float4*>(W2 + 2 * HDIM)[l32];
    const float asrc = a_src[n];

    float m = -3.0e38f;
    float s = 0.f;
    float4 acc = make_float4(0.f, 0.f, 0.f, 0.f);

    for (int base = lo; base < hi; base += 2 * BATCH) {
        float lv[BATCH];
        uint2 mu[BATCH];

        // ---- pass A: independent loads + logits for 8 edges of this half ----
#pragma unroll
        for (int i = 0; i < BATCH; ++i) {
            int e = base + half + 2 * i;
            bool valid = (e < hi);
            int ee = valid ? e : (hi - 1);           // clamped, always in-bounds
            float4 ev = reinterpret_cast<const float4*>(edge_emb)[(size_t)ee * 32 + l32];
            int d = end[ee];
            mu[i] = reinterpret_cast<const uint2*>(msgb)[(size_t)d * 32 + l32];
            float p = ev.x * wc.x + ev.y * wc.y + ev.z * wc.z + ev.w * wc.w;
#pragma unroll
            for (int k = 1; k <= 16; k <<= 1) p += __shfl_xor(p, k);  // within half
            float l = p + asrc + a_dst[d];
            l = (l >= 0.f) ? l : NEG_SLOPE * l;
            lv[i] = valid ? l : -3.0e38f;
        }

        // ---- pass B: batch max, one rescale, independent accumulates ----
        float bm = lv[0];
#pragma unroll
        for (int i = 1; i < BATCH; ++i) bm = fmaxf(bm, lv[i]);
        float mn = fmaxf(m, bm);
        float sc = __expf(m - mn);   // 0 on first batch (m=-3e38, mn finite)

        float bs = 0.f;
        float4 ba = make_float4(0.f, 0.f, 0.f, 0.f);
#pragma unroll
        for (int i = 0; i < BATCH; ++i) {
            float w = __expf(lv[i] - mn);            // masked: exp(-3e38-mn)=0
            bs += w;
            ba.x += w * __uint_as_float(mu[i].x << 16);
            ba.y += w * __uint_as_float(mu[i].x & 0xffff0000u);
            ba.z += w * __uint_as_float(mu[i].y << 16);
            ba.w += w * __uint_as_float(mu[i].y & 0xffff0000u);
        }
        s = s * sc + bs;
        acc.x = acc.x * sc + ba.x;
        acc.y = acc.y * sc + ba.y;
        acc.z = acc.z * sc + ba.z;
        acc.w = acc.w * sc + ba.w;
        m = mn;
    }

    // merge the two half-wave states (empty half: m=-3e38 -> weight 0)
    float mo = __shfl_xor(m, 32);
    float so = __shfl_xor(s, 32);
    float4 ao;
    ao.x = __shfl_xor(acc.x, 32);
    ao.y = __shfl_xor(acc.y, 32);
    ao.z = __shfl_xor(acc.z, 32);
    ao.w = __shfl_xor(acc.w, 32);
    float mm = fmaxf(m, mo);
    float e0 = __expf(m - mm);
    float e1 = __expf(mo - mm);
    float inv = 1.f / (s * e0 + so * e1);
    if (half == 0) {
        float4 r;
        r.x = (acc.x * e0 + ao.x * e1) * inv;
        r.y = (acc.y * e0 + ao.y * e1) * inv;
        r.z = (acc.z * e0 + ao.z * e1) * inv;
        r.w = (acc.w * e0 + ao.w * e1) * inv;
        *reinterpret_cast<float4*>(&out[(size_t)n * HDIM + l32 * 4]) = r;
    }
}

// ---------------------------------------------------------------------------
extern "C" void kernel_launch(void* const* d_in, const int* in_sizes, int n_in,
                              void* d_out, int out_size, void* d_ws, size_t ws_size,
                              hipStream_t stream) {
    const float* node_emb = (const float*)d_in[0];
    const float* edge_emb = (const float*)d_in[1];
    const int*   start    = (const int*)d_in[2];
    const int*   end      = (const int*)d_in[3];
    const float* W1       = (const float*)d_in[4];
    const float* W2       = (const float*)d_in[5];
    float* out = (float*)d_out;

    const int N = in_sizes[0] / HDIM;
    const int E = in_sizes[2];

    uint8_t* ws = (uint8_t*)d_ws;
    size_t off = 0;
    auto alloc = [&](size_t bytes) {
        void* p = ws + off;
        off = (off + bytes + 511) & ~(size_t)511;
        return p;
    };
    unsigned short* msgb = (unsigned short*)alloc((size_t)N * HDIM * sizeof(unsigned short));
    float* a_src   = (float*)alloc((size_t)N * sizeof(float));
    float* a_dst   = (float*)alloc((size_t)N * sizeof(float));
    int*   row_ptr = (int*)alloc((size_t)(N + 1) * sizeof(int));

    // K0: row_ptr (independent of K1)
    k0_rowptr<<<(E + 255) / 256, 256, 0, stream>>>(start, row_ptr, N, E);
    // K1: messages (bf16) + fused fp32 a_src/a_dst
    k1_messages<<<(N + K1_ROWS - 1) / K1_ROWS, 256, 0, stream>>>(
        node_emb, W1, W2, msgb, a_src, a_dst, N);
    // K23: fused edge logits + batched softmax + aggregate (one wave per node)
    k23_fused<<<(N + 3) / 4, 256, 0, stream>>>(edge_emb, W2, row_ptr, end,
                                               a_src, a_dst, msgb, out, N);
}